// Round 9
// baseline (1766.319 us; speedup 1.0000x reference)
//
#include <hip/hip_runtime.h>
#include <stdint.h>

#define B_ 64
#define N_ 16
#define T_ 128
#define I_ 256
#define H_ 256
#define G_ 768    // 3*H
#define NGRP 32   // T/4 time-groups

typedef __attribute__((ext_vector_type(8))) short bf8;        // 8 bf16 (4 VGPRs)
typedef __attribute__((ext_vector_type(8))) unsigned short u16x8;
typedef __attribute__((ext_vector_type(4))) float f4;

static __device__ __forceinline__ unsigned short f2bf(float f) {
    uint32_t u = __builtin_bit_cast(uint32_t, f);
    u += 0x7fffu + ((u >> 16) & 1u);   // RNE
    return (unsigned short)(u >> 16);
}
static __device__ __forceinline__ float bf2f(unsigned short s) {
    return __builtin_bit_cast(float, ((uint32_t)s) << 16);
}
static __device__ __forceinline__ float sigm(float x) {
    return __builtin_amdgcn_rcpf(1.f + __expf(-x));
}
static __device__ __forceinline__ bf8 cvt8(float4 u, float4 v) {
    bf8 a;
    a[0] = (short)f2bf(u.x); a[1] = (short)f2bf(u.y);
    a[2] = (short)f2bf(u.z); a[3] = (short)f2bf(u.w);
    a[4] = (short)f2bf(v.x); a[5] = (short)f2bf(v.y);
    a[6] = (short)f2bf(v.z); a[7] = (short)f2bf(v.w);
    return a;
}

// LDS-only barrier: does not drain vmcnt (global prefetch/stores stay in flight).
static __device__ __forceinline__ void barrier_lds_only() {
    asm volatile("s_waitcnt lgkmcnt(0)\n\ts_barrier" ::: "memory");
}

// ---- ws layout (bytes) ----
#define OFF_WIH   0ull
#define OFF_WHH   6291456ull
#define OFF_BIAS  12582912ull
#define WS_NEEDED (OFF_BIAS + 49152ull)

// ---------------- stage 0: convert/shuffle weights (unchanged layout) ----------------
// fragment order [n][ct(48)][kt(8)][lane(64)][e(8)]
//   B-frag: col = ct*16 + (lane&15), k = kt*32 + (lane>>4)*8 + e
__global__ __launch_bounds__(256) void prep_kernel(
        const float* __restrict__ wih, const float* __restrict__ whh,
        const float* __restrict__ bih, const float* __restrict__ bhh,
        unsigned char* ws) {
    unsigned short* wih_fr = (unsigned short*)(ws + OFF_WIH);
    unsigned short* whh_fr = (unsigned short*)(ws + OFF_WHH);
    float* bias_f = (float*)(ws + OFF_BIAS);
    int gid = blockIdx.x * blockDim.x + threadIdx.x;
    int nthr = gridDim.x * blockDim.x;

    for (int o = gid; o < 393216; o += nthr) {
        int lane = o & 63, kt = (o >> 6) & 7, ct = (o >> 9) % 48, n = o / 24576;
        int gcol = ct * 16 + (lane & 15);
        int k0 = kt * 32 + (lane >> 4) * 8;
        const float* s0 = wih + ((size_t)(n * G_ + gcol)) * I_ + k0;
        const float* s1 = whh + ((size_t)(n * G_ + gcol)) * H_ + k0;
        u16x8 v0, v1;
        #pragma unroll
        for (int e = 0; e < 8; e++) { v0[e] = f2bf(s0[e]); v1[e] = f2bf(s1[e]); }
        *(u16x8*)(wih_fr + (size_t)o * 8) = v0;
        *(u16x8*)(whh_fr + (size_t)o * 8) = v1;
    }
    for (int o = gid; o < N_ * G_; o += nthr) {
        int g = o % G_;
        bias_f[o] = bih[o] + (g < 512 ? bhh[o] : 0.f);
    }
}

// ---------------- fused GRU: input projection + scan, T=128, one dispatch ----------------
// 256 blocks = (n, rg); 1024 thr / 16 waves. Wave w owns gate cols [w*16, w*16+16)
// for all 3 gates (ct = g*16 + w). Per step: 24 hh MFMA/wave (A = replicated h rows)
// + amortized 6 ih MFMA/wave (A = 16 rows = 4 brows x 4 ts, computed one group ahead,
// staged in the LDS ring ihb[2]). x A-frags load straight from global (prefetched one
// step ahead). Gate math: thread (w,c16,q) owns (brow=rg*4+q, col=w*16+c16).
__global__ __launch_bounds__(1024, 1) void gru_fused(
        const float* __restrict__ x, const unsigned char* __restrict__ wsr,
        const float* __restrict__ bhh, float* __restrict__ out) {
    const unsigned short* wih_fr = (const unsigned short*)(wsr + OFF_WIH);
    const unsigned short* whh_fr = (const unsigned short*)(wsr + OFF_WHH);
    const float* bias_f = (const float*)(wsr + OFF_BIAS);

    __shared__ __align__(16) unsigned short ihb[2][4][4][784];  // [buf][ts][brow][gates+pad]
    __shared__ __align__(16) unsigned short hbf[2][4][272];     // [buf][hrow][col+pad]

    int tid = threadIdx.x, lane = tid & 63, w = tid >> 6;
    int c16 = lane & 15, q = lane >> 4, q8 = q * 8;
    int n = blockIdx.x & 15, rg = blockIdx.x >> 4;
    int col = w * 16 + c16;
    int brow = rg * 4 + q;
    int hrow = c16 >> 2;

    // register-resident weight fragments: 3 hh + 3 ih tiles x 8 kt
    bf8 wfh[3][8], wfi[3][8];
    #pragma unroll
    for (int g = 0; g < 3; g++) {
        int ct = g * 16 + w;
        #pragma unroll
        for (int kt = 0; kt < 8; kt++) {
            size_t base = ((((size_t)n * 48 + ct) * 8 + kt) * 64 + lane) * 8;
            wfh[g][kt] = *(const bf8*)(whh_fr + base);
            wfi[g][kt] = *(const bf8*)(wih_fr + base);
        }
    }

    float bias_r = bias_f[n * G_ + col];
    float bias_z = bias_f[n * G_ + 256 + col];
    float bias_n = bias_f[n * G_ + 512 + col];
    float bn_hh  = bhh[n * G_ + 512 + col];

    // lane's ih A-frag source: row = c16 (= ts*4 + brow_i), k = kt*32 + q*8 + e
    const float* xbase = x + ((((size_t)(rg * 4 + (c16 & 3)) * N_ + n) * T_) + (c16 >> 2)) * I_ + q8;

    f4 zf = {0.f, 0.f, 0.f, 0.f};
    float h = 0.f;
    hbf[0][q][col] = 0;

    // ---- prologue: ih for group 0 -> ihb[0] ----
    f4 ai0 = zf, ai1 = zf, ai2 = zf;
    #pragma unroll
    for (int kt = 0; kt < 8; kt++) {
        float4 f0 = *(const float4*)(xbase + kt * 32);
        float4 f1 = *(const float4*)(xbase + kt * 32 + 4);
        bf8 a = cvt8(f0, f1);
        ai0 = __builtin_amdgcn_mfma_f32_16x16x32_bf16(a, wfi[0][kt], ai0, 0, 0, 0);
        ai1 = __builtin_amdgcn_mfma_f32_16x16x32_bf16(a, wfi[1][kt], ai1, 0, 0, 0);
        ai2 = __builtin_amdgcn_mfma_f32_16x16x32_bf16(a, wfi[2][kt], ai2, 0, 0, 0);
    }
    // D: lane(q,c16) reg r -> ts = q, brow_i = r, col = ct*16+c16 = g*256 + w*16 + c16
    #pragma unroll
    for (int r = 0; r < 4; r++) {
        ihb[0][q][r][col]       = f2bf(ai0[r] + bias_r);
        ihb[0][q][r][256 + col] = f2bf(ai1[r] + bias_z);
        ihb[0][q][r][512 + col] = f2bf(ai2[r] + bias_n);
    }
    ai0 = zf; ai1 = zf; ai2 = zf;

    // preload x slice for step 0 (target group 1, kt {0,1})
    float4 xn0 = *(const float4*)(xbase + 1024);
    float4 xn1 = *(const float4*)(xbase + 1028);
    float4 xn2 = *(const float4*)(xbase + 1056);
    float4 xn3 = *(const float4*)(xbase + 1060);

    __syncthreads();

    float4 xf0, xf1, xf2, xf3;

    #pragma unroll 1
    for (int g = 0; g < NGRP; g++) {
        int buf = g & 1;
        int gt = g + 1;
        bool doih = (gt < NGRP);

        #pragma unroll
        for (int ts = 0; ts < 4; ts++) {
            int t = g * 4 + ts;

            // rotate prefetched x slice
            xf0 = xn0; xf1 = xn1; xf2 = xn2; xf3 = xn3;

            // gate prefetch from LDS ring (consumed after MFMA)
            const unsigned short* gp = &ihb[buf][ts][q][col];
            unsigned short ir = gp[0], iz = gp[256], inx = gp[512];

            // issue x loads for NEXT step's slice
            {
                int gt2 = (ts == 3) ? (g + 2) : gt;
                int ts2 = (ts + 1) & 3;
                if (gt2 < NGRP) {
                    const float* p = xbase + gt2 * 1024 + ts2 * 64;
                    xn0 = *(const float4*)(p);
                    xn1 = *(const float4*)(p + 4);
                    xn2 = *(const float4*)(p + 32);
                    xn3 = *(const float4*)(p + 36);
                }
            }

            // hh = h @ whh^T (A rows = replicated h)
            const unsigned short* hb = &hbf[t & 1][0][0];
            f4 ah0 = zf, ah1 = zf, ah2 = zf;
            #pragma unroll
            for (int kt = 0; kt < 8; kt++) {
                bf8 a = *(const bf8*)(hb + hrow * 272 + kt * 32 + q8);
                ah0 = __builtin_amdgcn_mfma_f32_16x16x32_bf16(a, wfh[0][kt], ah0, 0, 0, 0);
                ah1 = __builtin_amdgcn_mfma_f32_16x16x32_bf16(a, wfh[1][kt], ah1, 0, 0, 0);
                ah2 = __builtin_amdgcn_mfma_f32_16x16x32_bf16(a, wfh[2][kt], ah2, 0, 0, 0);
            }

            // ih slice for group g+1: kt = 2*ts, 2*ts+1 (static indices)
            if (doih) {
                bf8 a0 = cvt8(xf0, xf1);
                bf8 a1 = cvt8(xf2, xf3);
                ai0 = __builtin_amdgcn_mfma_f32_16x16x32_bf16(a0, wfi[2 * ts][0] * 0 + wfi[0][2 * ts], ai0, 0, 0, 0);
                // (expression above is just wfi[0][2*ts]; kept simple below)
                ai0 = ai0; // no-op guard
                ai1 = __builtin_amdgcn_mfma_f32_16x16x32_bf16(a0, wfi[1][2 * ts], ai1, 0, 0, 0);
                ai2 = __builtin_amdgcn_mfma_f32_16x16x32_bf16(a0, wfi[2][2 * ts], ai2, 0, 0, 0);
                ai0 = __builtin_amdgcn_mfma_f32_16x16x32_bf16(a1, wfi[0][2 * ts + 1], ai0, 0, 0, 0);
                ai1 = __builtin_amdgcn_mfma_f32_16x16x32_bf16(a1, wfi[1][2 * ts + 1], ai1, 0, 0, 0);
                ai2 = __builtin_amdgcn_mfma_f32_16x16x32_bf16(a1, wfi[2][2 * ts + 1], ai2, 0, 0, 0);

                if (ts == 3) {
                    #pragma unroll
                    for (int r = 0; r < 4; r++) {
                        ihb[gt & 1][q][r][col]       = f2bf(ai0[r] + bias_r);
                        ihb[gt & 1][q][r][256 + col] = f2bf(ai1[r] + bias_z);
                        ihb[gt & 1][q][r][512 + col] = f2bf(ai2[r] + bias_n);
                    }
                    ai0 = zf; ai1 = zf; ai2 = zf;
                }
            }

            // gates: thread owns (brow, col); hh D reg 0 = row q*4 (replicated h row q)
            float xr = bf2f(ir) + ah0[0];
            float xz = bf2f(iz) + ah1[0];
            float rr = sigm(xr), zz = sigm(xz);
            float pre = bf2f(inx) + rr * (ah2[0] + bn_hh);
            float e2 = __expf(2.f * pre);
            float nv = 1.f - 2.f * __builtin_amdgcn_rcpf(e2 + 1.f);
            float hn = nv + zz * (h - nv);
            h = hn;

            hbf[(t & 1) ^ 1][q][col] = f2bf(hn);
            out[((size_t)(brow * N_ + n) * T_ + t) * H_ + col] = hn;

            barrier_lds_only();
        }
    }
}

extern "C" void kernel_launch(void* const* d_in, const int* in_sizes, int n_in,
                              void* d_out, int out_size, void* d_ws, size_t ws_size,
                              hipStream_t stream) {
    const float* x   = (const float*)d_in[0];
    const float* wih = (const float*)d_in[1];
    const float* whh = (const float*)d_in[2];
    const float* bih = (const float*)d_in[3];
    const float* bhh = (const float*)d_in[4];
    float* out = (float*)d_out;
    unsigned char* ws = (unsigned char*)d_ws;

    if (ws_size < WS_NEEDED) return;

    prep_kernel<<<1024, 256, 0, stream>>>(wih, whh, bih, bhh, ws);
    gru_fused<<<dim3(256), 1024, 0, stream>>>(x, ws, bhh, out);
}

// Round 10
// 270.959 us; speedup vs baseline: 6.5188x; 6.5188x over previous
//
#include <hip/hip_runtime.h>
#include <stdint.h>

#define B_ 64
#define N_ 16
#define T_ 128
#define I_ 256
#define H_ 256
#define G_ 768   // 3*H
#define TC 64    // time chunk

typedef __attribute__((ext_vector_type(8))) short bf8;        // 8 bf16 in 4 VGPRs (MFMA frag)
typedef __attribute__((ext_vector_type(8))) unsigned short u16x8;
typedef __attribute__((ext_vector_type(4))) float f4;

static __device__ __forceinline__ unsigned short f2bf(float f) {
    uint32_t u = __builtin_bit_cast(uint32_t, f);
    u += 0x7fffu + ((u >> 16) & 1u);   // RNE
    return (unsigned short)(u >> 16);
}
static __device__ __forceinline__ float bf2f(unsigned short s) {
    return __builtin_bit_cast(float, ((uint32_t)s) << 16);
}
static __device__ __forceinline__ float sigm(float x) {
    return __builtin_amdgcn_rcpf(1.f + __expf(-x));
}

// LDS-only barrier: does not drain vmcnt (global prefetch/stores stay in flight).
static __device__ __forceinline__ void barrier_lds_only() {
    asm volatile("s_waitcnt lgkmcnt(0)\n\ts_barrier" ::: "memory");
}

// ---- ws layout (bytes) ----
// IH relayout: per (b,n) 96KB block of ushort, offset
//   ((rt*48 + ct)*4 + r)*64 + q*16 + c16
// where trow = rt*16 + q*4 + r (t within chunk), g = ct*16 + c16.
#define OFF_WIH   0ull
#define OFF_WHH   6291456ull
#define OFF_BIAS  12582912ull
#define OFF_H32   12632064ull
#define OFF_IH    13680640ull
#define WS_NEEDED (OFF_IH + 100663296ull)

// ---------------- stage 0: convert/shuffle weights ----------------
__global__ __launch_bounds__(256) void prep_kernel(
        const float* __restrict__ wih, const float* __restrict__ whh,
        const float* __restrict__ bih, const float* __restrict__ bhh,
        unsigned char* ws) {
    unsigned short* wih_fr = (unsigned short*)(ws + OFF_WIH);
    unsigned short* whh_fr = (unsigned short*)(ws + OFF_WHH);
    float* bias_f = (float*)(ws + OFF_BIAS);
    int gid = blockIdx.x * blockDim.x + threadIdx.x;
    int nthr = gridDim.x * blockDim.x;

    // fragment order [n][ct(48)][kt(8)][lane(64)][e(8)]
    //   B-frag: col = ct*16 + (lane&15), k = kt*32 + (lane>>4)*8 + e
    for (int o = gid; o < 393216; o += nthr) {
        int lane = o & 63, kt = (o >> 6) & 7, ct = (o >> 9) % 48, n = o / 24576;
        int gcol = ct * 16 + (lane & 15);
        int k0 = kt * 32 + (lane >> 4) * 8;
        const float* s0 = wih + ((size_t)(n * G_ + gcol)) * I_ + k0;
        const float* s1 = whh + ((size_t)(n * G_ + gcol)) * H_ + k0;
        u16x8 v0, v1;
        #pragma unroll
        for (int e = 0; e < 8; e++) { v0[e] = f2bf(s0[e]); v1[e] = f2bf(s1[e]); }
        *(u16x8*)(wih_fr + (size_t)o * 8) = v0;
        *(u16x8*)(whh_fr + (size_t)o * 8) = v1;
    }
    for (int o = gid; o < N_ * G_; o += nthr) {
        int g = o % G_;
        bias_f[o] = bih[o] + (g < 512 ? bhh[o] : 0.f);
    }
}

// ---------------- stage 1: IH = bf16( x @ wih^T + bias_f ) for one T-chunk ----------------
// grid 256 = 1 block/CU; block = (n, bq) covering 4 b-tiles of 64 rows x 768 cols.
// XCD-aware map: n = (blk&7)*2 + (blk>>7).
__global__ __launch_bounds__(1024, 1) void ih_gemm(
        const float* __restrict__ x, const unsigned char* __restrict__ wsr,
        unsigned char* ws, int t0) {
    const unsigned short* wih_fr = (const unsigned short*)(wsr + OFF_WIH);
    const float* bias_f = (const float*)(wsr + OFF_BIAS);
    unsigned short* IH = (unsigned short*)(ws + OFF_IH);

    __shared__ __align__(16) unsigned short As[4 * 64 * 256];   // 128 KB

    int tid = threadIdx.x, lane = tid & 63, w = tid >> 6;
    int blk = blockIdx.x;
    int n = (blk & 7) * 2 + (blk >> 7);
    int bq = (blk >> 3) & 15;
    int c16 = lane & 15, q = lane >> 4, q16 = q * 8;

    // stage A: 4 tiles x 64 rows x 256 k (fp32 -> bf16), swizzled
    #pragma unroll
    for (int i = 0; i < 4; i++) {
        int b = bq * 4 + i;
        const float* xb = x + (((size_t)(b * N_ + n)) * T_ + t0) * I_;
        #pragma unroll
        for (int j = 0; j < 2; j++) {
            int chunk = j * 1024 + tid;
            int row = chunk >> 5, kc = chunk & 31;
            const float* s = xb + row * I_ + kc * 8;
            float4 f0 = *(const float4*)s;
            float4 f1 = *(const float4*)(s + 4);
            u16x8 v;
            v[0] = f2bf(f0.x); v[1] = f2bf(f0.y); v[2] = f2bf(f0.z); v[3] = f2bf(f0.w);
            v[4] = f2bf(f1.x); v[5] = f2bf(f1.y); v[6] = f2bf(f1.z); v[7] = f2bf(f1.w);
            int eoff = i * 16384 + row * 256 + ((kc * 8) ^ ((row & 7) << 3));
            *(u16x8*)(As + eoff) = v;
        }
    }
    __syncthreads();

    // wave w owns col-tiles ct = w*3 .. w*3+2
    const unsigned short* bptr = wih_fr + (((size_t)n * 48 + w * 3) * 8) * 64 * 8;
    f4 zf = {0.f, 0.f, 0.f, 0.f};

    #pragma unroll 1
    for (int i = 0; i < 4; i++) {
        int b = bq * 4 + i;
        const unsigned short* Ai = As + i * 16384;

        f4 acc[4][3];
        #pragma unroll
        for (int rt = 0; rt < 4; rt++)
            #pragma unroll
            for (int c = 0; c < 3; c++) acc[rt][c] = zf;

        bf8 bc[3], bn[3];
        #pragma unroll
        for (int c = 0; c < 3; c++)
            bc[c] = *(const bf8*)(bptr + (((size_t)c * 8 + 0) * 64 + lane) * 8);

        #pragma unroll 1
        for (int kt = 0; kt < 8; kt++) {
            int ktn = (kt + 1) & 7;
            #pragma unroll
            for (int c = 0; c < 3; c++)
                bn[c] = *(const bf8*)(bptr + (((size_t)c * 8 + ktn) * 64 + lane) * 8);
            bf8 a[4];
            #pragma unroll
            for (int rt = 0; rt < 4; rt++) {
                int ar = rt * 16 + c16;
                a[rt] = *(const bf8*)(Ai + ar * 256 + ((kt * 32 + q16) ^ ((ar & 7) << 3)));
            }
            #pragma unroll
            for (int c = 0; c < 3; c++)
                #pragma unroll
                for (int rt = 0; rt < 4; rt++)
                    acc[rt][c] = __builtin_amdgcn_mfma_f32_16x16x32_bf16(a[rt], bc[c], acc[rt][c], 0, 0, 0);
            #pragma unroll
            for (int c = 0; c < 3; c++) bc[c] = bn[c];
        }

        // epilogue: +bias, store bf16 to relayout (128B contiguous per wave-store).
        unsigned short* ob = IH + (size_t)(b * N_ + n) * 49152 + lane;
        #pragma unroll
        for (int c = 0; c < 3; c++) {
            int ct = w * 3 + c;
            float bias = bias_f[n * G_ + ct * 16 + c16];
            #pragma unroll
            for (int rt = 0; rt < 4; rt++) {
                #pragma unroll
                for (int r = 0; r < 4; r++)
                    ob[(((rt * 48 + ct) * 4) + r) * 64] = f2bf(acc[rt][c][r] + bias);
            }
        }
    }
}

// ---------------- stage 2: sequential GRU scan ----------------
// R10: __launch_bounds__(512,1) -> 512-reg budget so all 48 wf fragments stay
// register-resident (no per-step L2 weight streaming). Occupancy already 1 block/CU.
__global__ __launch_bounds__(512, 1) void gru_scan(
        const unsigned char* __restrict__ wsr, unsigned char* ws,
        const float* __restrict__ bhh, float* __restrict__ out,
        int chunk, int t0) {
    const unsigned short* IH = (const unsigned short*)(wsr + OFF_IH);
    const unsigned short* whh_fr = (const unsigned short*)(wsr + OFF_WHH);
    float* h32ws = (float*)(ws + OFF_H32);

    __shared__ __align__(16) unsigned short hbf[2][4][272];

    int tid = threadIdx.x, lane = tid & 63, w = tid >> 6;
    int n = blockIdx.x & 15, rg = blockIdx.x >> 4;

    int c16 = lane & 15;
    int q = lane >> 4;
    int hrow = c16 >> 2;
    int q16 = q * 8;
    int brow = rg * 4 + q;

    bf8 wf[3][2][8];
    #pragma unroll
    for (int g = 0; g < 3; g++)
        #pragma unroll
        for (int u = 0; u < 2; u++) {
            int ct = g * 16 + w * 2 + u;
            #pragma unroll
            for (int kt = 0; kt < 8; kt++)
                wf[g][u][kt] = *(const bf8*)(whh_fr + ((((size_t)n * 48 + ct) * 8 + kt) * 64 + lane) * 8);
        }

    int colb = w * 32 + c16;
    float bn0 = bhh[n * G_ + 512 + colb];
    float bn1 = bhh[n * G_ + 512 + colb + 16];
    float h0 = 0.f, h1 = 0.f;
    if (chunk) {
        const float* hp = h32ws + ((size_t)brow * N_ + n) * H_ + colb;
        h0 = hp[0]; h1 = hp[16];
    }
    hbf[0][q][colb] = f2bf(h0);
    hbf[0][q][colb + 16] = f2bf(h1);

    // relayout read base: + c16; per-step offset TPART(t); per-gate ct offsets.
    const unsigned short* ihb = IH + (size_t)(brow * N_ + n) * 49152 + c16;
    int cb2 = w * 512;   // ct = w*2 -> (w*2)*256

    #define TPART(t) (((t) >> 4) * 12288 + ((t) & 3) * 64 + (((t) >> 2) & 3) * 16)

    unsigned short c_r0, c_r1, c_z0, c_z1, c_n0, c_n1;
    {
        const unsigned short* p = ihb + TPART(0) + cb2;
        c_r0 = p[0];    c_r1 = p[256];
        c_z0 = p[4096]; c_z1 = p[4352];
        c_n0 = p[8192]; c_n1 = p[8448];
    }

    f4 zf = {0.f, 0.f, 0.f, 0.f};
    __syncthreads();

    #pragma unroll 1
    for (int t = 0; t < TC; t++) {
        int tn = (t + 1 < TC) ? (t + 1) : t;
        const unsigned short* p = ihb + TPART(tn) + cb2;
        unsigned short n_r0 = p[0],    n_r1 = p[256];
        unsigned short n_z0 = p[4096], n_z1 = p[4352];
        unsigned short n_n0 = p[8192], n_n1 = p[8448];

        const unsigned short* hb = &hbf[t & 1][0][0];
        f4 acc[3][2];
        #pragma unroll
        for (int g = 0; g < 3; g++)
            #pragma unroll
            for (int u = 0; u < 2; u++) acc[g][u] = zf;
        #pragma unroll
        for (int kt = 0; kt < 8; kt++) {
            bf8 a = *(const bf8*)(hb + hrow * 272 + kt * 32 + q16);
            #pragma unroll
            for (int g = 0; g < 3; g++)
                #pragma unroll
                for (int u = 0; u < 2; u++)
                    acc[g][u] = __builtin_amdgcn_mfma_f32_16x16x32_bf16(a, wf[g][u][kt], acc[g][u], 0, 0, 0);
        }

        float xr0 = bf2f(c_r0) + acc[0][0][0];
        float xz0 = bf2f(c_z0) + acc[1][0][0];
        float rr0 = sigm(xr0), zz0 = sigm(xz0);
        float pre0 = bf2f(c_n0) + rr0 * (acc[2][0][0] + bn0);
        float e20 = __expf(2.f * pre0);
        float nv0 = 1.f - 2.f * __builtin_amdgcn_rcpf(e20 + 1.f);
        float hn0 = nv0 + zz0 * (h0 - nv0);

        float xr1 = bf2f(c_r1) + acc[0][1][0];
        float xz1 = bf2f(c_z1) + acc[1][1][0];
        float rr1 = sigm(xr1), zz1 = sigm(xz1);
        float pre1 = bf2f(c_n1) + rr1 * (acc[2][1][0] + bn1);
        float e21 = __expf(2.f * pre1);
        float nv1 = 1.f - 2.f * __builtin_amdgcn_rcpf(e21 + 1.f);
        float hn1 = nv1 + zz1 * (h1 - nv1);

        h0 = hn0; h1 = hn1;

        unsigned short* hw = &hbf[(t & 1) ^ 1][q][colb];
        hw[0] = f2bf(hn0);
        hw[16] = f2bf(hn1);

        float* op = out + ((size_t)(brow * N_ + n) * T_ + (t0 + t)) * H_ + colb;
        op[0] = hn0;
        op[16] = hn1;

        c_r0 = n_r0; c_r1 = n_r1;
        c_z0 = n_z0; c_z1 = n_z1;
        c_n0 = n_n0; c_n1 = n_n1;

        barrier_lds_only();   // LDS-only wait: IH prefetch + out stores stay in flight
    }

    float* hp = h32ws + ((size_t)brow * N_ + n) * H_ + colb;
    hp[0] = h0;
    hp[16] = h1;
}

extern "C" void kernel_launch(void* const* d_in, const int* in_sizes, int n_in,
                              void* d_out, int out_size, void* d_ws, size_t ws_size,
                              hipStream_t stream) {
    const float* x   = (const float*)d_in[0];
    const float* wih = (const float*)d_in[1];
    const float* whh = (const float*)d_in[2];
    const float* bih = (const float*)d_in[3];
    const float* bhh = (const float*)d_in[4];
    float* out = (float*)d_out;
    unsigned char* ws = (unsigned char*)d_ws;

    if (ws_size < WS_NEEDED) return;

    prep_kernel<<<1024, 256, 0, stream>>>(wih, whh, bih, bhh, ws);
    for (int chunk = 0; chunk < 2; chunk++) {
        int t0 = chunk * TC;
        ih_gemm<<<dim3(256), 1024, 0, stream>>>(x, ws, ws, t0);
        gru_scan<<<dim3(256), 512, 0, stream>>>(ws, ws, bhh, out, chunk, t0);
    }
}